// Round 11
// baseline (229.914 us; speedup 1.0000x reference)
//
#include <hip/hip_runtime.h>
#include <hip/hip_bf16.h>

#define B_ROWS 65536
#define NA 128
#define D_OUT 1024
#define VBS 128
#define NCHUNK (B_ROWS / VBS)   // 512

typedef __attribute__((ext_vector_type(8))) short bf16x8s;
typedef __attribute__((ext_vector_type(4))) float f32x4;
typedef __attribute__((ext_vector_type(4))) unsigned short u16x4;
typedef __attribute__((ext_vector_type(8))) unsigned short u16x8;

static __device__ __forceinline__ short f2bf(float f) {
    unsigned u = __builtin_bit_cast(unsigned, f);
    u = u + 0x7FFFu + ((u >> 16) & 1u);   // round-to-nearest-even to bf16
    return (short)(u >> 16);
}
static __device__ __forceinline__ float bf2f(unsigned short h) {
    unsigned u = ((unsigned)h) << 16;
    return __builtin_bit_cast(float, u);
}
// packed RNE f32->bf16 pair: 1 VALU op for 2 elements
static __device__ __forceinline__ unsigned cvt_pk_bf16(float a, float b) {
    unsigned r;
    asm("v_cvt_pk_bf16_f32 %0, %1, %2" : "=v"(r) : "v"(a), "v"(b));
    return r;
}

// One block per virtual batch (chunk): 128 threads, one per feature.
__global__ void gbn_stats_kernel(const float* __restrict__ a,
                                 const float* __restrict__ gamma,
                                 const float* __restrict__ beta,
                                 float* __restrict__ ss) {
    int c = blockIdx.x;
    int j = threadIdx.x;            // feature 0..127
    const float* p = a + (size_t)c * (VBS * NA) + j;
    float s = 0.f, s2 = 0.f;
#pragma unroll 8
    for (int r = 0; r < VBS; ++r) {
        float v = p[r * NA];
        s += v; s2 += v * v;
    }
    float mean = s * (1.f / VBS);
    float var  = fmaxf(s2 * (1.f / VBS) - mean * mean, 0.f);   // biased var
    float sc = gamma[j] * rsqrtf(var + 1e-5f);
    float sh = beta[j] - mean * sc;
    float2* o = (float2*)ss + (c * NA + j);
    *o = make_float2(sc, sh);
}

// Pack W (f32 [1024][128]) into bf16 fragment-contiguous chunks for the
// 16-wave kernel: chunk c = ((w*4 + ks)*4 + nf)*64 + lane, lane=(g*16+q),
// holding W[w*64 + nf*16 + q][ks*32 + g*8 .. +8].
__global__ void wpack_kernel(const float* __restrict__ W, u16x8* __restrict__ Wp) {
    int c = blockIdx.x * 256 + threadIdx.x;   // 16384 chunks
    int lane = c & 63;
    int nf   = (c >> 6) & 3;
    int ks   = (c >> 8) & 3;
    int w    = (c >> 10) & 15;
    int g = lane >> 4, q = lane & 15;
    const float* src = W + (size_t)(w * 64 + nf * 16 + q) * NA + ks * 32 + g * 8;
    u16x8 h;
#pragma unroll
    for (int i = 0; i < 8; ++i) h[i] = (unsigned short)f2bf(src[i]);
    Wp[c] = h;
}

// One block per 16 rows, 1024 threads = 16 waves. GEMM: wave w owns cols
// [w*64, w*64+64) -> acc[4] (16 AGPR). Swapped-operand MFMA: thread (g,q)
// holds y[r0+q][w*64+nf*16+4g+r]. Epilogue: *prior, bf16 LDS transpose,
// then wave w runs Michelot on row w alone (va[16], full-wave reduce).
// launch_bounds(1024,8): force <=64 unified regs -> 2 blocks/CU = 32 waves/CU.
__global__ __launch_bounds__(1024, 8) void fused_kernel(
    const float* __restrict__ a,
    const float* __restrict__ prior,
    const float* __restrict__ ss,
    const u16x8* __restrict__ Wp,
    float* __restrict__ out) {

    const int tid  = threadIdx.x;
    const int w    = tid >> 6;        // wave 0..15: col block AND output row
    const int lane = tid & 63;
    const int g    = lane >> 4;       // 0..3
    const int q    = lane & 15;       // output row within tile (GEMM phase)

    const int r0    = blockIdx.x * 16;
    const int chunk = r0 >> 7;

    f32x4 acc[4];
#pragma unroll
    for (int i = 0; i < 4; ++i) acc[i] = (f32x4){0.f, 0.f, 0.f, 0.f};

    const float* ssb = ss + (size_t)chunk * NA * 2;

    // ---- GEMM: y[16 x 1024] = GBN(a_tile)[16 x 128] * W^T (operands swapped) ----
#pragma unroll
    for (int ks = 0; ks < 4; ++ks) {
        const int k0 = ks * 32 + g * 8;
        const float4* ap = (const float4*)(a + (size_t)(r0 + q) * NA + k0);
        float4 v0 = ap[0], v1 = ap[1];
        const float4* sp = (const float4*)(ssb + k0 * 2);   // interleaved (sc,sh)
        float4 s0 = sp[0], s1 = sp[1], s2 = sp[2], s3 = sp[3];
        int4 ai;
        ai.x = (int)cvt_pk_bf16(v0.x * s0.x + s0.y, v0.y * s0.z + s0.w);
        ai.y = (int)cvt_pk_bf16(v0.z * s1.x + s1.y, v0.w * s1.z + s1.w);
        ai.z = (int)cvt_pk_bf16(v1.x * s2.x + s2.y, v1.y * s2.z + s2.w);
        ai.w = (int)cvt_pk_bf16(v1.z * s3.x + s3.y, v1.w * s3.z + s3.w);
        bf16x8s af = __builtin_bit_cast(bf16x8s, ai);

        const bf16x8s* wp = (const bf16x8s*)(Wp + ((size_t)(w * 4 + ks) * 4) * 64 + lane);
#pragma unroll
        for (int nf = 0; nf < 4; ++nf) {
            bf16x8s bf = wp[nf * 64];
            acc[nf] = __builtin_amdgcn_mfma_f32_16x16x32_bf16(bf, af, acc[nf], 0, 0, 0);
        }
    }

    // ---- prior load (post-GEMM: TLP at 8 waves/SIMD hides it) + multiply ----
    {
        const float* pb = prior + (size_t)(r0 + q) * D_OUT + w * 64 + 4 * g;
#pragma unroll
        for (int nf = 0; nf < 4; ++nf) {
            float4 p = *(const float4*)(pb + nf * 16);
            acc[nf][0] *= p.x; acc[nf][1] *= p.y;
            acc[nf][2] *= p.z; acc[nf][3] *= p.w;
        }
    }

    // ---- transpose through LDS (bf16, padded layout) ----
    __shared__ unsigned short ls[16][1032];   // 1032 = 1024 + 8 pad, 33 KB
#pragma unroll
    for (int nf = 0; nf < 4; ++nf) {
        uint2 hh;
        hh.x = cvt_pk_bf16(acc[nf][0], acc[nf][1]);
        hh.y = cvt_pk_bf16(acc[nf][2], acc[nf][3]);
        *(uint2*)&ls[q][w * 64 + nf * 16 + 4 * g] = hh;
    }
    __syncthreads();

    // ---- wave w processes row w alone: va[16] per lane ----
    float va[16];
#pragma unroll
    for (int j = 0; j < 4; ++j) {
        u16x4 hv = *(const u16x4*)&ls[w][j * 256 + lane * 4];
        va[j * 4 + 0] = bf2f(hv[0]);
        va[j * 4 + 1] = bf2f(hv[1]);
        va[j * 4 + 2] = bf2f(hv[2]);
        va[j * 4 + 3] = bf2f(hv[3]);
    }

    // ---- init: tau_0 = (sum_all - 1)/1024 ----
    float s = 0.f;
#pragma unroll
    for (int e = 0; e < 16; ++e) s += va[e];
#pragma unroll
    for (int m = 1; m < 64; m <<= 1) s += __shfl_xor(s, m);
    float tau = (s - 1.f) * (1.f / 1024.f);
    int cprev = 1024;

    // ---- Michelot: tau += (F(tau)-1)/C; count on SALU via ballot+popc ----
#pragma unroll 1
    for (int it = 0; it < 32; ++it) {
        float S = 0.f;
        int   C = 0;
#pragma unroll
        for (int e = 0; e < 16; ++e) {
            float d = va[e] - tau;
            S += fmaxf(d, 0.f);
            C += (int)__popcll(__ballot(d > 0.f));
        }
#pragma unroll
        for (int m = 1; m < 64; m <<= 1) S += __shfl_xor(S, m);
        tau += (S - 1.f) * __builtin_amdgcn_rcpf((float)C);
        if (C == cprev) break;
        cprev = C;
    }

    // ---- output: reference computes relu(x - (1-cum_k)/k) = relu(x + tau_std).
    //      tau here is tau_std -> ADD it (empirically validated R6/R9).
    float* ob = out + (size_t)(r0 + w) * D_OUT + lane * 4;
#pragma unroll
    for (int j = 0; j < 4; ++j) {
        float4 o;
        o.x = fmaxf(va[j * 4 + 0] + tau, 0.f);
        o.y = fmaxf(va[j * 4 + 1] + tau, 0.f);
        o.z = fmaxf(va[j * 4 + 2] + tau, 0.f);
        o.w = fmaxf(va[j * 4 + 3] + tau, 0.f);
        *(float4*)(ob + j * 256) = o;
    }
}

extern "C" void kernel_launch(void* const* d_in, const int* in_sizes, int n_in,
                              void* d_out, int out_size, void* d_ws, size_t ws_size,
                              hipStream_t stream) {
    const float* a     = (const float*)d_in[0];
    const float* prior = (const float*)d_in[1];
    const float* gamma = (const float*)d_in[2];
    const float* beta  = (const float*)d_in[3];
    const float* W     = (const float*)d_in[4];
    float* out = (float*)d_out;

    float* ss = (float*)d_ws;                            // 512 KB @ 0
    u16x8* Wp = (u16x8*)((char*)d_ws + 524288);          // 256 KB @ 512K

    gbn_stats_kernel<<<NCHUNK, VBS, 0, stream>>>(a, gamma, beta, ss);
    wpack_kernel<<<64, 256, 0, stream>>>(W, Wp);
    fused_kernel<<<B_ROWS / 16, 1024, 0, stream>>>(a, prior, ss, Wp, out);
}